// Round 7
// baseline (4901.087 us; speedup 1.0000x reference)
//
#include <hip/hip_runtime.h>

#define S_N 50000
#define E_N 20000
#define K_N 128
#define B_N 16384
#define NE_N 1000000

// radix partition geometry
#define NBS 256        // S-side dest buckets (pow2)
#define NBS_LOG 8
#define SRANGE 196     // 196*256 = 50176 >= 50000
#define NBE 128        // E-side dest buckets (pow2)
#define NBE_LOG 7
#define ERANGE 157     // 157*128 = 20096 >= 20000

typedef short bf16x8 __attribute__((ext_vector_type(8)));
typedef float f32x4 __attribute__((ext_vector_type(4)));

__device__ __forceinline__ float sigmoidf_(float v) {
    return 1.0f / (1.0f + __expf(-v));
}
__device__ __forceinline__ float tanh_fast(float v) {
    float e = __expf(2.0f * v);
    return 1.0f - 2.0f / (e + 1.0f);
}
// fp32 -> bf16 RNE
__device__ __forceinline__ unsigned short f2bf(float v) {
    unsigned u = __float_as_uint(v);
    u += 0x7fffu + ((u >> 16) & 1u);
    return (unsigned short)(u >> 16);
}
// split fp32 into hi (truncated bf16) + lo (bf16 of residual)
__device__ __forceinline__ void split_bf(float v, unsigned short& hi, unsigned short& lo) {
    unsigned u = __float_as_uint(v);
    hi = (unsigned short)(u >> 16);
    float fh = __uint_as_float(u & 0xffff0000u);
    lo = f2bf(v - fh);
}

// ---- CSR build ----------------------------------------------------------

__global__ __launch_bounds__(256) void histogram_kernel(
    const int* __restrict__ r1, const int* __restrict__ c1,
    const int* __restrict__ r0, const int* __restrict__ c0,
    int* __restrict__ cntS, int* __restrict__ cntE) {
    int i = blockIdx.x * blockDim.x + threadIdx.x;
    if (i < NE_N) {
        atomicAdd(&cntS[__builtin_nontemporal_load(r1 + i)], 1);
        atomicAdd(&cntE[__builtin_nontemporal_load(c1 + i)], 1);
    } else if (i < 2 * NE_N) {
        int j = i - NE_N;
        atomicAdd(&cntS[__builtin_nontemporal_load(r0 + j)], 1);
        atomicAdd(&cntE[__builtin_nontemporal_load(c0 + j)], 1);
    }
}

// ---- parallel scan: per-1024-chunk sums ----
__global__ __launch_bounds__(1024) void scan_sums(
    const int* __restrict__ cnt, int n, int* __restrict__ sums) {
    __shared__ int ws[16];
    int t = threadIdx.x;
    int idx = blockIdx.x * 1024 + t;
    int v = (idx < n) ? cnt[idx] : 0;
#pragma unroll
    for (int d = 32; d > 0; d >>= 1) v += __shfl_down(v, d);
    if ((t & 63) == 0) ws[t >> 6] = v;
    __syncthreads();
    if (t == 0) {
        int s = 0;
#pragma unroll
        for (int i = 0; i < 16; ++i) s += ws[i];
        sums[blockIdx.x] = s;
    }
}

// ---- parallel scan: exclusive-scan the chunk sums (both sides, 1 block) ----
__global__ __launch_bounds__(128) void scan_tops(
    int* __restrict__ sumsS, int nS, int* __restrict__ offSn,
    int* __restrict__ sumsE, int nE, int* __restrict__ offEn) {
    int lane = threadIdx.x & 63;
    int* sums; int n; int* offn;
    if (threadIdx.x < 64) { sums = sumsS; n = nS; offn = offSn; }
    else                  { sums = sumsE; n = nE; offn = offEn; }
    int v = (lane < n) ? sums[lane] : 0;
    int s = v;
#pragma unroll
    for (int d = 1; d < 64; d <<= 1) {
        int o = __shfl_up(s, d);
        if (lane >= d) s += o;
    }
    if (lane < n) sums[lane] = s - v;   // exclusive
    if (lane == 63) *offn = s;          // grand total -> off[n]
}

// ---- parallel scan: apply (intra-chunk scan + chunk offset) ----
__global__ __launch_bounds__(1024) void scan_apply(
    const int* __restrict__ cnt, int n, const int* __restrict__ sums,
    int* __restrict__ off, int* __restrict__ cur) {
    __shared__ int ws[16];
    int t = threadIdx.x, lane = t & 63, wid = t >> 6;
    int idx = blockIdx.x * 1024 + t;
    int v = (idx < n) ? cnt[idx] : 0;
    int s = v;
#pragma unroll
    for (int d = 1; d < 64; d <<= 1) {
        int o = __shfl_up(s, d);
        if (lane >= d) s += o;
    }
    if (lane == 63) ws[wid] = s;
    __syncthreads();
    if (t == 0) {
        int a = 0;
#pragma unroll
        for (int i = 0; i < 16; ++i) { int x = ws[i]; ws[i] = a; a += x; }
    }
    __syncthreads();
    int excl = sums[blockIdx.x] + ws[wid] + s - v;
    if (idx < n) { off[idx] = excl; cur[idx] = excl; }
}

// bucket cursors = CSR offset at each bucket's first node
__global__ __launch_bounds__(256) void init_pcur(
    const int* __restrict__ offS, const int* __restrict__ offE,
    int* __restrict__ pcurS, int* __restrict__ pcurE) {
    int t = threadIdx.x;
    if (t < NBS) pcurS[t] = offS[t * SRANGE];
    if (t < NBE) pcurE[t] = offE[t * ERANGE];
}

// ---- phase 1: partition edges into dest-range buckets -------------------
// Bucket b is pinned to XCD b&7; blocks with x=blockIdx&7 stream the full
// edge list (nt) and append only edges whose dest bucket is theirs. Staging
// segments are pre-aligned to CSR bucket boundaries (cursor from off[]), so
// each XCD's append frontier is ~48 hot lines that assemble fully in its L2.
__global__ __launch_bounds__(256) void partition_kernel(
    const int* __restrict__ r1, const int* __restrict__ c1,
    const float* __restrict__ vui1, const float* __restrict__ viu1,
    const int* __restrict__ r0, const int* __restrict__ c0,
    const float* __restrict__ vui0, const float* __restrict__ viu0,
    int* __restrict__ pcurS, int* __restrict__ pcurE,
    int2* __restrict__ stageS, int2* __restrict__ stageE) {
    const int x = blockIdx.x & 7;
    const int i = (blockIdx.x >> 3) * 256 + threadIdx.x;
    if (i >= 2 * NE_N) return;
    int r, c; float a, b;
    if (i < NE_N) {
        r = __builtin_nontemporal_load(r1 + i);
        c = __builtin_nontemporal_load(c1 + i);
        a = __builtin_nontemporal_load(vui1 + i);
        b = __builtin_nontemporal_load(viu1 + i);
    } else {
        int j = i - NE_N;
        r = __builtin_nontemporal_load(r0 + j);
        c = __builtin_nontemporal_load(c0 + j);
        a = __builtin_nontemporal_load(vui0 + j);
        b = __builtin_nontemporal_load(viu0 + j);
    }
    int bs = r / SRANGE;               // const divisor -> magic mul
    if ((bs & 7) == x) {
        int slot = atomicAdd(&pcurS[bs], 1);
        stageS[slot] = make_int2((r << 15) | c, __float_as_int(a));  // r<=50k(16b), c<20k(15b)
    }
    int be = c / ERANGE;
    if ((be & 7) == x) {
        int slot = atomicAdd(&pcurE[be], 1);
        stageE[slot] = make_int2((c << 16) | r, __float_as_int(b));  // c(15b)<<16 | r(16b)
    }
}

// ---- phase 2: CSR-ify one bucket's staging segment ----------------------
// blockIdx = j*nb + b  ->  blockIdx&7 = b&7 = the bucket's XCD. Both the
// staging reads and the CSR scatter target the same ~62-125 KB node window,
// resident in that XCD's L2; lines are single-visit.
__global__ __launch_bounds__(256) void csrify_kernel(
    const int2* __restrict__ stage, const int* __restrict__ off,
    int* __restrict__ cur, int2* __restrict__ csr,
    int nbLog, int range, int nnode, int keyShift, int srcMask) {
    const int nb = 1 << nbLog;
    const int b = blockIdx.x & (nb - 1);
    const int j = blockIdx.x >> nbLog;
    const int nblk = gridDim.x >> nbLog;
    const int segStart = off[b * range];
    const int hiNode = (b + 1) * range;
    const int segEnd = off[hiNode < nnode ? hiNode : nnode];
    for (int i = segStart + j * 256 + (int)threadIdx.x; i < segEnd; i += nblk * 256) {
        long long q = __builtin_nontemporal_load((const long long*)(stage + i));
        int key = (int)q;
        int dest = key >> keyShift;
        int src = key & srcMask;
        int slot = atomicAdd(&cur[dest], 1);
        csr[slot] = make_int2(src, (int)(q >> 32));
    }
}

__global__ __launch_bounds__(256) void mark_needed(
    const int* __restrict__ ids, int n, unsigned* __restrict__ mask) {
    int i = blockIdx.x * blockDim.x + threadIdx.x;
    if (i < n) {
        int v = ids[i];
        atomicOr(&mask[v >> 5], 1u << (v & 31));
    }
}

// ---- propagation: one wave per destination row, 64 lanes x float2 ------
__global__ __launch_bounds__(256) void gather_pass(
    const float* __restrict__ src, const float* __restrict__ self,
    const float* __restrict__ dA, const float* __restrict__ dB,
    const int* __restrict__ off, const int2* __restrict__ csr,
    const unsigned* __restrict__ need,
    float* __restrict__ dst, int nrow) {
    int w = blockIdx.x * 4 + (threadIdx.x >> 6);
    int lane = threadIdx.x & 63;
    if (w >= nrow) return;
    if (need && !((need[w >> 5] >> (w & 31)) & 1u)) return;
    float d = dA[w] + dB[w];
    float2 sv = ((const float2*)(self + (size_t)w * K_N))[lane];
    float ax = sv.x * d, ay = sv.y * d;
    int i = off[w], end = off[w + 1];
    for (; i + 4 <= end; i += 4) {
        long long q0 = __builtin_nontemporal_load((const long long*)(csr + i));
        long long q1 = __builtin_nontemporal_load((const long long*)(csr + i + 1));
        long long q2 = __builtin_nontemporal_load((const long long*)(csr + i + 2));
        long long q3 = __builtin_nontemporal_load((const long long*)(csr + i + 3));
        int n0 = (int)q0, n1 = (int)q1, n2 = (int)q2, n3 = (int)q3;
        float2 s0 = ((const float2*)(src + (size_t)n0 * K_N))[lane];
        float2 s1 = ((const float2*)(src + (size_t)n1 * K_N))[lane];
        float2 s2 = ((const float2*)(src + (size_t)n2 * K_N))[lane];
        float2 s3 = ((const float2*)(src + (size_t)n3 * K_N))[lane];
        float v0 = __int_as_float((int)(q0 >> 32));
        float v1 = __int_as_float((int)(q1 >> 32));
        float v2 = __int_as_float((int)(q2 >> 32));
        float v3 = __int_as_float((int)(q3 >> 32));
        ax = fmaf(v0, s0.x, ax); ay = fmaf(v0, s0.y, ay);
        ax = fmaf(v1, s1.x, ax); ay = fmaf(v1, s1.y, ay);
        ax = fmaf(v2, s2.x, ax); ay = fmaf(v2, s2.y, ay);
        ax = fmaf(v3, s3.x, ax); ay = fmaf(v3, s3.y, ay);
    }
    for (; i < end; ++i) {
        long long q = __builtin_nontemporal_load((const long long*)(csr + i));
        float2 s = ((const float2*)(src + (size_t)(int)q * K_N))[lane];
        float v = __int_as_float((int)(q >> 32));
        ax = fmaf(v, s.x, ax); ay = fmaf(v, s.y, ay);
    }
    ((float2*)(dst + (size_t)w * K_N))[lane] = make_float2(ax, ay);
}

// ---- prediction stage 0: |W| -> split bf16 tables -----------------------
__global__ __launch_bounds__(256) void abs_split_kernel(
    const float* __restrict__ W1, const float* __restrict__ W2,
    unsigned short* __restrict__ w1hi, unsigned short* __restrict__ w1lo,
    unsigned short* __restrict__ w2hi, unsigned short* __restrict__ w2lo) {
    int i = blockIdx.x * 256 + threadIdx.x;
    unsigned short hi, lo;
    if (i < 32768) {
        split_bf(fabsf(W1[i]), hi, lo);
        w1hi[i] = hi; w1lo[i] = lo;
    } else {
        int j = i - 32768;
        split_bf(fabsf(W2[j]), hi, lo);
        w2hi[j] = hi; w2lo[j] = lo;
    }
}

// ---- prediction stage 1: feature x -> split bf16 [B_N x 128] ------------
__global__ __launch_bounds__(256) void feature_kernel(
    const int* __restrict__ stu_id, const int* __restrict__ ex_id,
    const float* __restrict__ ikp,
    const float* __restrict__ stat, const float* __restrict__ kdiff,
    const float* __restrict__ s_bias, const float* __restrict__ e_disc,
    unsigned short* __restrict__ xhi, unsigned short* __restrict__ xlo) {
    int i = blockIdx.x * 256 + threadIdx.x;
    int row = i >> 5;
    int k4 = (i & 31) * 4;
    int s = stu_id[row];
    int e = ex_id[row];
    float sb = s_bias[s];
    float ed = sigmoidf_(e_disc[e]);
    float4 sv = *(const float4*)(stat + (size_t)s * K_N + k4);
    float4 kv = *(const float4*)(kdiff + (size_t)e * K_N + k4);
    float4 iv = *(const float4*)(ikp + (size_t)row * K_N + k4);
    float f0 = iv.x * (sigmoidf_(sv.x + sb) - sigmoidf_(kv.x)) * ed;
    float f1 = iv.y * (sigmoidf_(sv.y + sb) - sigmoidf_(kv.y)) * ed;
    float f2 = iv.z * (sigmoidf_(sv.z + sb) - sigmoidf_(kv.z)) * ed;
    float f3 = iv.w * (sigmoidf_(sv.w + sb) - sigmoidf_(kv.w)) * ed;
    ushort4 oh, ol;
    split_bf(f0, oh.x, ol.x);
    split_bf(f1, oh.y, ol.y);
    split_bf(f2, oh.z, ol.z);
    split_bf(f3, oh.w, ol.w);
    *(ushort4*)(xhi + (size_t)row * K_N + k4) = oh;
    *(ushort4*)(xlo + (size_t)row * K_N + k4) = ol;
}

// ---- prediction stage 2: split-bf16 MFMA MLP ----------------------------
#define H1S 264   // h1 LDS row stride in ushorts

__global__ __launch_bounds__(256) void mlp_mfma(
    const unsigned short* __restrict__ xhi, const unsigned short* __restrict__ xlo,
    const unsigned short* __restrict__ w1hi, const unsigned short* __restrict__ w1lo,
    const unsigned short* __restrict__ w2hi, const unsigned short* __restrict__ w2lo,
    const float* __restrict__ b1, const float* __restrict__ b2,
    const float* __restrict__ W3, const float* __restrict__ b3,
    float* __restrict__ out) {
    __shared__ unsigned short h1hi[32 * H1S];
    __shared__ unsigned short h1lo[32 * H1S];
    __shared__ float partial[4][32];

    const int t = threadIdx.x;
    const int lane = t & 63;
    const int w = t >> 6;
    const int l15 = lane & 15;
    const int quad = lane >> 4;
    const int r0 = blockIdx.x * 32;

    f32x4 acc1[2][4] = {};
    for (int ks = 0; ks < 128; ks += 32) {
        bf16x8 ah[2], al[2], bh[4], bl[4];
#pragma unroll
        for (int mt = 0; mt < 2; ++mt) {
            size_t o = (size_t)(r0 + mt * 16 + l15) * K_N + ks + quad * 8;
            ah[mt] = *(const bf16x8*)(xhi + o);
            al[mt] = *(const bf16x8*)(xlo + o);
        }
#pragma unroll
        for (int nt = 0; nt < 4; ++nt) {
            size_t o = (size_t)(w * 64 + nt * 16 + l15) * 128 + ks + quad * 8;
            bh[nt] = *(const bf16x8*)(w1hi + o);
            bl[nt] = *(const bf16x8*)(w1lo + o);
        }
#pragma unroll
        for (int mt = 0; mt < 2; ++mt)
#pragma unroll
            for (int nt = 0; nt < 4; ++nt) {
                acc1[mt][nt] = __builtin_amdgcn_mfma_f32_16x16x32_bf16(
                    ah[mt], bh[nt], acc1[mt][nt], 0, 0, 0);
                acc1[mt][nt] = __builtin_amdgcn_mfma_f32_16x16x32_bf16(
                    ah[mt], bl[nt], acc1[mt][nt], 0, 0, 0);
                acc1[mt][nt] = __builtin_amdgcn_mfma_f32_16x16x32_bf16(
                    al[mt], bh[nt], acc1[mt][nt], 0, 0, 0);
            }
    }
#pragma unroll
    for (int nt = 0; nt < 4; ++nt) {
        int c = w * 64 + nt * 16 + l15;
        float bias = b1[c];
#pragma unroll
        for (int mt = 0; mt < 2; ++mt)
#pragma unroll
            for (int rg = 0; rg < 4; ++rg) {
                int row = mt * 16 + quad * 4 + rg;
                float h = tanh_fast(acc1[mt][nt][rg] + bias);
                unsigned short hi, lo;
                split_bf(h, hi, lo);
                h1hi[row * H1S + c] = hi;
                h1lo[row * H1S + c] = lo;
            }
    }
    __syncthreads();

    f32x4 acc2[2][2] = {};
    for (int ks = 0; ks < 256; ks += 32) {
        bf16x8 ah[2], al[2], bh[2], bl[2];
#pragma unroll
        for (int mt = 0; mt < 2; ++mt) {
            int o = (mt * 16 + l15) * H1S + ks + quad * 8;
            ah[mt] = *(const bf16x8*)(&h1hi[o]);
            al[mt] = *(const bf16x8*)(&h1lo[o]);
        }
#pragma unroll
        for (int nt = 0; nt < 2; ++nt) {
            size_t o = (size_t)(w * 32 + nt * 16 + l15) * 256 + ks + quad * 8;
            bh[nt] = *(const bf16x8*)(w2hi + o);
            bl[nt] = *(const bf16x8*)(w2lo + o);
        }
#pragma unroll
        for (int mt = 0; mt < 2; ++mt)
#pragma unroll
            for (int nt = 0; nt < 2; ++nt) {
                acc2[mt][nt] = __builtin_amdgcn_mfma_f32_16x16x32_bf16(
                    ah[mt], bh[nt], acc2[mt][nt], 0, 0, 0);
                acc2[mt][nt] = __builtin_amdgcn_mfma_f32_16x16x32_bf16(
                    ah[mt], bl[nt], acc2[mt][nt], 0, 0, 0);
                acc2[mt][nt] = __builtin_amdgcn_mfma_f32_16x16x32_bf16(
                    al[mt], bh[nt], acc2[mt][nt], 0, 0, 0);
            }
    }

    float w3v[2], b2v[2];
#pragma unroll
    for (int nt = 0; nt < 2; ++nt) {
        int c = w * 32 + nt * 16 + l15;
        w3v[nt] = fabsf(W3[c]);
        b2v[nt] = b2[c];
    }
#pragma unroll
    for (int mt = 0; mt < 2; ++mt)
#pragma unroll
        for (int rg = 0; rg < 4; ++rg) {
            float v = w3v[0] * tanh_fast(acc2[mt][0][rg] + b2v[0]) +
                      w3v[1] * tanh_fast(acc2[mt][1][rg] + b2v[1]);
            v += __shfl_xor(v, 1, 16);
            v += __shfl_xor(v, 2, 16);
            v += __shfl_xor(v, 4, 16);
            v += __shfl_xor(v, 8, 16);
            if (l15 == 0) partial[w][mt * 16 + quad * 4 + rg] = v;
        }
    __syncthreads();
    if (t < 32) {
        float v = partial[0][t] + partial[1][t] + partial[2][t] + partial[3][t];
        out[r0 + t] = sigmoidf_(v + b3[0]);
    }
}

extern "C" void kernel_launch(void* const* d_in, const int* in_sizes, int n_in,
                              void* d_out, int out_size, void* d_ws, size_t ws_size,
                              hipStream_t stream) {
    const int* stu_id        = (const int*)d_in[0];
    const int* input_ex      = (const int*)d_in[1];
    const float* ikp         = (const float*)d_in[2];
    const int* rows_1        = (const int*)d_in[3];
    const int* cols_1        = (const int*)d_in[4];
    const int* rows_0        = (const int*)d_in[5];
    const int* cols_0        = (const int*)d_in[6];
    const float* vals_ui_1   = (const float*)d_in[7];
    const float* vals_iu_1   = (const float*)d_in[8];
    const float* vals_ui_0   = (const float*)d_in[9];
    const float* vals_iu_0   = (const float*)d_in[10];
    const float* d_i_1       = (const float*)d_in[11];
    const float* d_j_1       = (const float*)d_in[12];
    const float* d_i_0       = (const float*)d_in[13];
    const float* d_j_0       = (const float*)d_in[14];
    const float* student_emb = (const float*)d_in[15];
    const float* exercise_emb= (const float*)d_in[16];
    const float* s_bias      = (const float*)d_in[17];
    const float* e_disc      = (const float*)d_in[18];
    const float* W1          = (const float*)d_in[19];
    const float* b1          = (const float*)d_in[20];
    const float* W2          = (const float*)d_in[21];
    const float* b2          = (const float*)d_in[22];
    const float* W3          = (const float*)d_in[23];
    const float* b3          = (const float*)d_in[24];

    // ---- workspace layout ----
    char* p = (char*)d_ws;
    float* statA  = (float*)p; p += (size_t)S_N * K_N * 4;
    float* kdiffA = (float*)p; p += (size_t)E_N * K_N * 4;
    float* statB  = (float*)p; p += (size_t)S_N * K_N * 4;   // also: staging overlay
    float* kdiffB = (float*)p; p += (size_t)E_N * K_N * 4;
    int2* csrS    = (int2*)p;  p += (size_t)2 * NE_N * 8;
    int2* csrE    = (int2*)p;  p += (size_t)2 * NE_N * 8;
    int* cntS     = (int*)p;   p += (size_t)S_N * 4;
    int* cntE     = (int*)p;   p += (size_t)E_N * 4;
    int* offS     = (int*)p;   p += (size_t)(S_N + 1) * 4;
    int* offE     = (int*)p;   p += (size_t)(E_N + 1) * 4;
    int* curS     = (int*)p;   p += (size_t)S_N * 4;
    int* curE     = (int*)p;   p += (size_t)E_N * 4;
    unsigned* maskS = (unsigned*)p; p += 2048 * 4;
    unsigned* maskE = (unsigned*)p; p += 1024 * 4;
    int* sumsS    = (int*)p;   p += 64 * 4;
    int* sumsE    = (int*)p;   p += 64 * 4;
    int* pcurS    = (int*)p;   p += NBS * 4;
    int* pcurE    = (int*)p;   p += NBE * 4;
    // staging overlays statB+kdiffB (35.8 MB >= 32 MB); dead before layer-2 gathers
    int2* stageS  = (int2*)statB;
    int2* stageE  = stageS + (size_t)2 * NE_N;
    // prediction overlays on statA/kdiffA (dead after gathers)
    unsigned short* xhi = (unsigned short*)statA;
    unsigned short* xlo = xhi + (size_t)B_N * K_N;
    unsigned short* w1hi = (unsigned short*)kdiffA;
    unsigned short* w1lo = w1hi + 32768;
    unsigned short* w2hi = w1lo + 32768;
    unsigned short* w2lo = w2hi + 32768;

    // ---- zero-init counters and masks ----
    hipMemsetAsync(cntS, 0, (size_t)S_N * 4, stream);
    hipMemsetAsync(cntE, 0, (size_t)E_N * 4, stream);
    hipMemsetAsync(maskS, 0, 2048 * 4, stream);
    hipMemsetAsync(maskE, 0, 1024 * 4, stream);

    // ---- CSR build ----
    const int edgeChunks = (2 * NE_N + 255) / 256;  // 7813
    histogram_kernel<<<edgeChunks, 256, 0, stream>>>(rows_1, cols_1, rows_0, cols_0, cntS, cntE);
    const int nChunkS = (S_N + 1023) / 1024;        // 49
    const int nChunkE = (E_N + 1023) / 1024;        // 20
    scan_sums<<<nChunkS, 1024, 0, stream>>>(cntS, S_N, sumsS);
    scan_sums<<<nChunkE, 1024, 0, stream>>>(cntE, E_N, sumsE);
    scan_tops<<<1, 128, 0, stream>>>(sumsS, nChunkS, offS + S_N, sumsE, nChunkE, offE + E_N);
    scan_apply<<<nChunkS, 1024, 0, stream>>>(cntS, S_N, sumsS, offS, curS);
    scan_apply<<<nChunkE, 1024, 0, stream>>>(cntE, E_N, sumsE, offE, curE);
    init_pcur<<<1, 256, 0, stream>>>(offS, offE, pcurS, pcurE);
    partition_kernel<<<edgeChunks * 8, 256, 0, stream>>>(
        rows_1, cols_1, vals_ui_1, vals_iu_1,
        rows_0, cols_0, vals_ui_0, vals_iu_0,
        pcurS, pcurE, stageS, stageE);
    csrify_kernel<<<NBS * 32, 256, 0, stream>>>(stageS, offS, curS, csrS,
                                                NBS_LOG, SRANGE, S_N, 15, 32767);
    csrify_kernel<<<NBE * 64, 256, 0, stream>>>(stageE, offE, curE, csrE,
                                                NBE_LOG, ERANGE, E_N, 16, 65535);

    // ---- needed-row masks (for layer 2) ----
    mark_needed<<<(B_N + 255) / 256, 256, 0, stream>>>(stu_id, B_N, maskS);
    mark_needed<<<(B_N + 255) / 256, 256, 0, stream>>>(input_ex, B_N, maskE);

    const int sGrid = (S_N + 3) / 4;
    const int eGrid = (E_N + 3) / 4;

    // ---- layer 1: inputs -> A (all rows) ----
    gather_pass<<<sGrid, 256, 0, stream>>>(exercise_emb, student_emb, d_i_1, d_i_0,
                                           offS, csrS, nullptr, statA, S_N);
    gather_pass<<<eGrid, 256, 0, stream>>>(student_emb, exercise_emb, d_j_1, d_j_0,
                                           offE, csrE, nullptr, kdiffA, E_N);

    // ---- layer 2: A -> B (only rows the batch reads; staging is dead now) ----
    gather_pass<<<sGrid, 256, 0, stream>>>(kdiffA, statA, d_i_1, d_i_0,
                                           offS, csrS, maskS, statB, S_N);
    gather_pass<<<eGrid, 256, 0, stream>>>(statA, kdiffA, d_j_1, d_j_0,
                                           offE, csrE, maskE, kdiffB, E_N);

    // ---- prediction: feature/weights -> split bf16, MFMA MLP ----
    feature_kernel<<<B_N * 32 / 256, 256, 0, stream>>>(
        stu_id, input_ex, ikp, statB, kdiffB, s_bias, e_disc, xhi, xlo);
    abs_split_kernel<<<256, 256, 0, stream>>>(W1, W2, w1hi, w1lo, w2hi, w2lo);
    mlp_mfma<<<B_N / 32, 256, 0, stream>>>(xhi, xlo, w1hi, w1lo, w2hi, w2lo,
                                           b1, b2, W3, b3, (float*)d_out);
}

// Round 8
// 825.197 us; speedup vs baseline: 5.9393x; 5.9393x over previous
//
#include <hip/hip_runtime.h>
#include <hip/hip_fp16.h>

#define S_N 50000
#define E_N 20000
#define K_N 128
#define B_N 16384
#define NE_N 1000000

#define S_PER_XCD 6250   // ceil(S_N/8)
#define E_PER_XCD 2500   // ceil(E_N/8)

typedef short bf16x8 __attribute__((ext_vector_type(8)));
typedef float f32x4 __attribute__((ext_vector_type(4)));

__device__ __forceinline__ float sigmoidf_(float v) {
    return 1.0f / (1.0f + __expf(-v));
}
__device__ __forceinline__ float tanh_fast(float v) {
    float e = __expf(2.0f * v);
    return 1.0f - 2.0f / (e + 1.0f);
}
// fp32 -> bf16 RNE
__device__ __forceinline__ unsigned short f2bf(float v) {
    unsigned u = __float_as_uint(v);
    u += 0x7fffu + ((u >> 16) & 1u);
    return (unsigned short)(u >> 16);
}
// split fp32 into hi (truncated bf16) + lo (bf16 of residual)
__device__ __forceinline__ void split_bf(float v, unsigned short& hi, unsigned short& lo) {
    unsigned u = __float_as_uint(v);
    hi = (unsigned short)(u >> 16);
    float fh = __uint_as_float(u & 0xffff0000u);
    lo = f2bf(v - fh);
}

// ---- CSR build ----------------------------------------------------------

__global__ __launch_bounds__(256) void histogram_kernel(
    const int* __restrict__ r1, const int* __restrict__ c1,
    const int* __restrict__ r0, const int* __restrict__ c0,
    int* __restrict__ cntS, int* __restrict__ cntE) {
    int i = blockIdx.x * blockDim.x + threadIdx.x;
    if (i < NE_N) {
        atomicAdd(&cntS[__builtin_nontemporal_load(r1 + i)], 1);
        atomicAdd(&cntE[__builtin_nontemporal_load(c1 + i)], 1);
    } else if (i < 2 * NE_N) {
        int j = i - NE_N;
        atomicAdd(&cntS[__builtin_nontemporal_load(r0 + j)], 1);
        atomicAdd(&cntE[__builtin_nontemporal_load(c0 + j)], 1);
    }
}

// ---- parallel scan: per-1024-chunk sums ----
__global__ __launch_bounds__(1024) void scan_sums(
    const int* __restrict__ cnt, int n, int* __restrict__ sums) {
    __shared__ int ws[16];
    int t = threadIdx.x;
    int idx = blockIdx.x * 1024 + t;
    int v = (idx < n) ? cnt[idx] : 0;
#pragma unroll
    for (int d = 32; d > 0; d >>= 1) v += __shfl_down(v, d);
    if ((t & 63) == 0) ws[t >> 6] = v;
    __syncthreads();
    if (t == 0) {
        int s = 0;
#pragma unroll
        for (int i = 0; i < 16; ++i) s += ws[i];
        sums[blockIdx.x] = s;
    }
}

// ---- parallel scan: exclusive-scan the chunk sums (both sides, 1 block) ----
__global__ __launch_bounds__(128) void scan_tops(
    int* __restrict__ sumsS, int nS, int* __restrict__ offSn,
    int* __restrict__ sumsE, int nE, int* __restrict__ offEn) {
    int lane = threadIdx.x & 63;
    int* sums; int n; int* offn;
    if (threadIdx.x < 64) { sums = sumsS; n = nS; offn = offSn; }
    else                  { sums = sumsE; n = nE; offn = offEn; }
    int v = (lane < n) ? sums[lane] : 0;
    int s = v;
#pragma unroll
    for (int d = 1; d < 64; d <<= 1) {
        int o = __shfl_up(s, d);
        if (lane >= d) s += o;
    }
    if (lane < n) sums[lane] = s - v;   // exclusive
    if (lane == 63) *offn = s;          // grand total -> off[n]
}

// ---- parallel scan: apply (intra-chunk scan + chunk offset) ----
__global__ __launch_bounds__(1024) void scan_apply(
    const int* __restrict__ cnt, int n, const int* __restrict__ sums,
    int* __restrict__ off, int* __restrict__ cur) {
    __shared__ int ws[16];
    int t = threadIdx.x, lane = t & 63, wid = t >> 6;
    int idx = blockIdx.x * 1024 + t;
    int v = (idx < n) ? cnt[idx] : 0;
    int s = v;
#pragma unroll
    for (int d = 1; d < 64; d <<= 1) {
        int o = __shfl_up(s, d);
        if (lane >= d) s += o;
    }
    if (lane == 63) ws[wid] = s;
    __syncthreads();
    if (t == 0) {
        int a = 0;
#pragma unroll
        for (int i = 0; i < 16; ++i) { int x = ws[i]; ws[i] = a; a += x; }
    }
    __syncthreads();
    int excl = sums[blockIdx.x] + ws[wid] + s - v;
    if (idx < n) { off[idx] = excl; cur[idx] = excl; }
}

// One-shot XCD-partitioned scatter (R5/R6 design — node-level cursors, 280 KB
// of counters; NOTE: bucket-level cursors (R7) serialized on 6 cache lines).
__global__ __launch_bounds__(256) void fill_kernel_xcd(
    const int* __restrict__ r1, const int* __restrict__ c1,
    const float* __restrict__ vui1, const float* __restrict__ viu1,
    const int* __restrict__ r0, const int* __restrict__ c0,
    const float* __restrict__ vui0, const float* __restrict__ viu0,
    int* __restrict__ curS, int* __restrict__ curE,
    int2* __restrict__ csrS, int2* __restrict__ csrE) {
    const int x = blockIdx.x & 7;
    const int chunk = blockIdx.x >> 3;
    const int i = chunk * 256 + threadIdx.x;
    if (i >= 2 * NE_N) return;
    const int sLo = x * S_PER_XCD, sHi = sLo + S_PER_XCD;
    const int eLo = x * E_PER_XCD, eHi = eLo + E_PER_XCD;
    int r, c; float a, b;
    if (i < NE_N) {
        r = __builtin_nontemporal_load(r1 + i);
        c = __builtin_nontemporal_load(c1 + i);
        a = __builtin_nontemporal_load(vui1 + i);
        b = __builtin_nontemporal_load(viu1 + i);
    } else {
        int j = i - NE_N;
        r = __builtin_nontemporal_load(r0 + j);
        c = __builtin_nontemporal_load(c0 + j);
        a = __builtin_nontemporal_load(vui0 + j);
        b = __builtin_nontemporal_load(viu0 + j);
    }
    if (r >= sLo && r < sHi) {
        int s = atomicAdd(&curS[r], 1);
        csrS[s] = make_int2(c, __float_as_int(a));
    }
    if (c >= eLo && c < eHi) {
        int s = atomicAdd(&curE[c], 1);
        csrE[s] = make_int2(r, __float_as_int(b));
    }
}

__global__ __launch_bounds__(256) void mark_needed(
    const int* __restrict__ ids, int n, unsigned* __restrict__ mask) {
    int i = blockIdx.x * blockDim.x + threadIdx.x;
    if (i < n) {
        int v = ids[i];
        atomicOr(&mask[v >> 5], 1u << (v & 31));
    }
}

// ---- fp32 embeddings -> fp16 tables (one-time, ~54 MB traffic) ----------
__global__ __launch_bounds__(256) void cvt_f16(
    const float2* __restrict__ sE, const float2* __restrict__ eE,
    __half2* __restrict__ sH, __half2* __restrict__ eH) {
    int i = blockIdx.x * 256 + threadIdx.x;
    const int nS = S_N * 64;
    if (i < nS) {
        float2 v = sE[i];
        sH[i] = __floats2half2_rn(v.x, v.y);
    } else {
        int j = i - nS;
        if (j < E_N * 64) {
            float2 v = eE[j];
            eH[j] = __floats2half2_rn(v.x, v.y);
        }
    }
}

// ---- propagation: one wave per destination row, 64 lanes x half2 --------
// fp16 tables, fp32 accumulate. CSR stream non-temporal.
__global__ __launch_bounds__(256) void gather_pass_h(
    const __half2* __restrict__ src, const __half2* __restrict__ self,
    const float* __restrict__ dA, const float* __restrict__ dB,
    const int* __restrict__ off, const int2* __restrict__ csr,
    const unsigned* __restrict__ need,
    __half2* __restrict__ dst, int nrow) {
    int w = blockIdx.x * 4 + (threadIdx.x >> 6);
    int lane = threadIdx.x & 63;
    if (w >= nrow) return;
    if (need && !((need[w >> 5] >> (w & 31)) & 1u)) return;
    float d = dA[w] + dB[w];
    float2 sv = __half22float2(self[(size_t)w * 64 + lane]);
    float ax = sv.x * d, ay = sv.y * d;
    int i = off[w], end = off[w + 1];
    for (; i + 4 <= end; i += 4) {
        long long q0 = __builtin_nontemporal_load((const long long*)(csr + i));
        long long q1 = __builtin_nontemporal_load((const long long*)(csr + i + 1));
        long long q2 = __builtin_nontemporal_load((const long long*)(csr + i + 2));
        long long q3 = __builtin_nontemporal_load((const long long*)(csr + i + 3));
        float2 s0 = __half22float2(src[(size_t)(int)q0 * 64 + lane]);
        float2 s1 = __half22float2(src[(size_t)(int)q1 * 64 + lane]);
        float2 s2 = __half22float2(src[(size_t)(int)q2 * 64 + lane]);
        float2 s3 = __half22float2(src[(size_t)(int)q3 * 64 + lane]);
        float v0 = __int_as_float((int)(q0 >> 32));
        float v1 = __int_as_float((int)(q1 >> 32));
        float v2 = __int_as_float((int)(q2 >> 32));
        float v3 = __int_as_float((int)(q3 >> 32));
        ax = fmaf(v0, s0.x, ax); ay = fmaf(v0, s0.y, ay);
        ax = fmaf(v1, s1.x, ax); ay = fmaf(v1, s1.y, ay);
        ax = fmaf(v2, s2.x, ax); ay = fmaf(v2, s2.y, ay);
        ax = fmaf(v3, s3.x, ax); ay = fmaf(v3, s3.y, ay);
    }
    for (; i < end; ++i) {
        long long q = __builtin_nontemporal_load((const long long*)(csr + i));
        float2 s = __half22float2(src[(size_t)(int)q * 64 + lane]);
        float v = __int_as_float((int)(q >> 32));
        ax = fmaf(v, s.x, ax); ay = fmaf(v, s.y, ay);
    }
    dst[(size_t)w * 64 + lane] = __floats2half2_rn(ax, ay);
}

// ---- prediction stage 0: |W| -> split bf16 tables -----------------------
__global__ __launch_bounds__(256) void abs_split_kernel(
    const float* __restrict__ W1, const float* __restrict__ W2,
    unsigned short* __restrict__ w1hi, unsigned short* __restrict__ w1lo,
    unsigned short* __restrict__ w2hi, unsigned short* __restrict__ w2lo) {
    int i = blockIdx.x * 256 + threadIdx.x;
    unsigned short hi, lo;
    if (i < 32768) {
        split_bf(fabsf(W1[i]), hi, lo);
        w1hi[i] = hi; w1lo[i] = lo;
    } else {
        int j = i - 32768;
        split_bf(fabsf(W2[j]), hi, lo);
        w2hi[j] = hi; w2lo[j] = lo;
    }
}

// ---- prediction stage 1: feature x -> split bf16 [B_N x 128] ------------
__global__ __launch_bounds__(256) void feature_kernel(
    const int* __restrict__ stu_id, const int* __restrict__ ex_id,
    const float* __restrict__ ikp,
    const __half2* __restrict__ statH, const __half2* __restrict__ kdiffH,
    const float* __restrict__ s_bias, const float* __restrict__ e_disc,
    unsigned short* __restrict__ xhi, unsigned short* __restrict__ xlo) {
    int i = blockIdx.x * 256 + threadIdx.x;
    int row = i >> 5;
    int k4 = (i & 31) * 4;       // elements k4..k4+3
    int s = stu_id[row];
    int e = ex_id[row];
    float sb = s_bias[s];
    float ed = sigmoidf_(e_disc[e]);
    float2 s01 = __half22float2(statH[(size_t)s * 64 + (k4 >> 1)]);
    float2 s23 = __half22float2(statH[(size_t)s * 64 + (k4 >> 1) + 1]);
    float2 k01 = __half22float2(kdiffH[(size_t)e * 64 + (k4 >> 1)]);
    float2 k23 = __half22float2(kdiffH[(size_t)e * 64 + (k4 >> 1) + 1]);
    float4 iv = *(const float4*)(ikp + (size_t)row * K_N + k4);
    float f0 = iv.x * (sigmoidf_(s01.x + sb) - sigmoidf_(k01.x)) * ed;
    float f1 = iv.y * (sigmoidf_(s01.y + sb) - sigmoidf_(k01.y)) * ed;
    float f2 = iv.z * (sigmoidf_(s23.x + sb) - sigmoidf_(k23.x)) * ed;
    float f3 = iv.w * (sigmoidf_(s23.y + sb) - sigmoidf_(k23.y)) * ed;
    ushort4 oh, ol;
    split_bf(f0, oh.x, ol.x);
    split_bf(f1, oh.y, ol.y);
    split_bf(f2, oh.z, ol.z);
    split_bf(f3, oh.w, ol.w);
    *(ushort4*)(xhi + (size_t)row * K_N + k4) = oh;
    *(ushort4*)(xlo + (size_t)row * K_N + k4) = ol;
}

// ---- prediction stage 2: split-bf16 MFMA MLP ----------------------------
#define H1S 264   // h1 LDS row stride in ushorts

__global__ __launch_bounds__(256) void mlp_mfma(
    const unsigned short* __restrict__ xhi, const unsigned short* __restrict__ xlo,
    const unsigned short* __restrict__ w1hi, const unsigned short* __restrict__ w1lo,
    const unsigned short* __restrict__ w2hi, const unsigned short* __restrict__ w2lo,
    const float* __restrict__ b1, const float* __restrict__ b2,
    const float* __restrict__ W3, const float* __restrict__ b3,
    float* __restrict__ out) {
    __shared__ unsigned short h1hi[32 * H1S];
    __shared__ unsigned short h1lo[32 * H1S];
    __shared__ float partial[4][32];

    const int t = threadIdx.x;
    const int lane = t & 63;
    const int w = t >> 6;
    const int l15 = lane & 15;
    const int quad = lane >> 4;
    const int r0 = blockIdx.x * 32;

    f32x4 acc1[2][4] = {};
    for (int ks = 0; ks < 128; ks += 32) {
        bf16x8 ah[2], al[2], bh[4], bl[4];
#pragma unroll
        for (int mt = 0; mt < 2; ++mt) {
            size_t o = (size_t)(r0 + mt * 16 + l15) * K_N + ks + quad * 8;
            ah[mt] = *(const bf16x8*)(xhi + o);
            al[mt] = *(const bf16x8*)(xlo + o);
        }
#pragma unroll
        for (int nt = 0; nt < 4; ++nt) {
            size_t o = (size_t)(w * 64 + nt * 16 + l15) * 128 + ks + quad * 8;
            bh[nt] = *(const bf16x8*)(w1hi + o);
            bl[nt] = *(const bf16x8*)(w1lo + o);
        }
#pragma unroll
        for (int mt = 0; mt < 2; ++mt)
#pragma unroll
            for (int nt = 0; nt < 4; ++nt) {
                acc1[mt][nt] = __builtin_amdgcn_mfma_f32_16x16x32_bf16(
                    ah[mt], bh[nt], acc1[mt][nt], 0, 0, 0);
                acc1[mt][nt] = __builtin_amdgcn_mfma_f32_16x16x32_bf16(
                    ah[mt], bl[nt], acc1[mt][nt], 0, 0, 0);
                acc1[mt][nt] = __builtin_amdgcn_mfma_f32_16x16x32_bf16(
                    al[mt], bh[nt], acc1[mt][nt], 0, 0, 0);
            }
    }
#pragma unroll
    for (int nt = 0; nt < 4; ++nt) {
        int c = w * 64 + nt * 16 + l15;
        float bias = b1[c];
#pragma unroll
        for (int mt = 0; mt < 2; ++mt)
#pragma unroll
            for (int rg = 0; rg < 4; ++rg) {
                int row = mt * 16 + quad * 4 + rg;
                float h = tanh_fast(acc1[mt][nt][rg] + bias);
                unsigned short hi, lo;
                split_bf(h, hi, lo);
                h1hi[row * H1S + c] = hi;
                h1lo[row * H1S + c] = lo;
            }
    }
    __syncthreads();

    f32x4 acc2[2][2] = {};
    for (int ks = 0; ks < 256; ks += 32) {
        bf16x8 ah[2], al[2], bh[2], bl[2];
#pragma unroll
        for (int mt = 0; mt < 2; ++mt) {
            int o = (mt * 16 + l15) * H1S + ks + quad * 8;
            ah[mt] = *(const bf16x8*)(&h1hi[o]);
            al[mt] = *(const bf16x8*)(&h1lo[o]);
        }
#pragma unroll
        for (int nt = 0; nt < 2; ++nt) {
            size_t o = (size_t)(w * 32 + nt * 16 + l15) * 256 + ks + quad * 8;
            bh[nt] = *(const bf16x8*)(w2hi + o);
            bl[nt] = *(const bf16x8*)(w2lo + o);
        }
#pragma unroll
        for (int mt = 0; mt < 2; ++mt)
#pragma unroll
            for (int nt = 0; nt < 2; ++nt) {
                acc2[mt][nt] = __builtin_amdgcn_mfma_f32_16x16x32_bf16(
                    ah[mt], bh[nt], acc2[mt][nt], 0, 0, 0);
                acc2[mt][nt] = __builtin_amdgcn_mfma_f32_16x16x32_bf16(
                    ah[mt], bl[nt], acc2[mt][nt], 0, 0, 0);
                acc2[mt][nt] = __builtin_amdgcn_mfma_f32_16x16x32_bf16(
                    al[mt], bh[nt], acc2[mt][nt], 0, 0, 0);
            }
    }

    float w3v[2], b2v[2];
#pragma unroll
    for (int nt = 0; nt < 2; ++nt) {
        int c = w * 32 + nt * 16 + l15;
        w3v[nt] = fabsf(W3[c]);
        b2v[nt] = b2[c];
    }
#pragma unroll
    for (int mt = 0; mt < 2; ++mt)
#pragma unroll
        for (int rg = 0; rg < 4; ++rg) {
            float v = w3v[0] * tanh_fast(acc2[mt][0][rg] + b2v[0]) +
                      w3v[1] * tanh_fast(acc2[mt][1][rg] + b2v[1]);
            v += __shfl_xor(v, 1, 16);
            v += __shfl_xor(v, 2, 16);
            v += __shfl_xor(v, 4, 16);
            v += __shfl_xor(v, 8, 16);
            if (l15 == 0) partial[w][mt * 16 + quad * 4 + rg] = v;
        }
    __syncthreads();
    if (t < 32) {
        float v = partial[0][t] + partial[1][t] + partial[2][t] + partial[3][t];
        out[r0 + t] = sigmoidf_(v + b3[0]);
    }
}

extern "C" void kernel_launch(void* const* d_in, const int* in_sizes, int n_in,
                              void* d_out, int out_size, void* d_ws, size_t ws_size,
                              hipStream_t stream) {
    const int* stu_id        = (const int*)d_in[0];
    const int* input_ex      = (const int*)d_in[1];
    const float* ikp         = (const float*)d_in[2];
    const int* rows_1        = (const int*)d_in[3];
    const int* cols_1        = (const int*)d_in[4];
    const int* rows_0        = (const int*)d_in[5];
    const int* cols_0        = (const int*)d_in[6];
    const float* vals_ui_1   = (const float*)d_in[7];
    const float* vals_iu_1   = (const float*)d_in[8];
    const float* vals_ui_0   = (const float*)d_in[9];
    const float* vals_iu_0   = (const float*)d_in[10];
    const float* d_i_1       = (const float*)d_in[11];
    const float* d_j_1       = (const float*)d_in[12];
    const float* d_i_0       = (const float*)d_in[13];
    const float* d_j_0       = (const float*)d_in[14];
    const float* student_emb = (const float*)d_in[15];
    const float* exercise_emb= (const float*)d_in[16];
    const float* s_bias      = (const float*)d_in[17];
    const float* e_disc      = (const float*)d_in[18];
    const float* W1          = (const float*)d_in[19];
    const float* b1          = (const float*)d_in[20];
    const float* W2          = (const float*)d_in[21];
    const float* b2          = (const float*)d_in[22];
    const float* W3          = (const float*)d_in[23];
    const float* b3          = (const float*)d_in[24];

    // ---- workspace layout (fp16 node tables) ----
    char* p = (char*)d_ws;
    __half2* statAH  = (__half2*)p; p += (size_t)S_N * K_N * 2;   // 12.8 MB
    __half2* kdiffAH = (__half2*)p; p += (size_t)E_N * K_N * 2;   // 5.1 MB
    __half2* statBH  = (__half2*)p; p += (size_t)S_N * K_N * 2;
    __half2* kdiffBH = (__half2*)p; p += (size_t)E_N * K_N * 2;
    __half2* sEH     = (__half2*)p; p += (size_t)S_N * K_N * 2;   // converted inputs
    __half2* eEH     = (__half2*)p; p += (size_t)E_N * K_N * 2;
    int2* csrS    = (int2*)p;  p += (size_t)2 * NE_N * 8;
    int2* csrE    = (int2*)p;  p += (size_t)2 * NE_N * 8;
    int* cntS     = (int*)p;   p += (size_t)S_N * 4;
    int* cntE     = (int*)p;   p += (size_t)E_N * 4;
    int* offS     = (int*)p;   p += (size_t)(S_N + 1) * 4;
    int* offE     = (int*)p;   p += (size_t)(E_N + 1) * 4;
    int* curS     = (int*)p;   p += (size_t)S_N * 4;
    int* curE     = (int*)p;   p += (size_t)E_N * 4;
    unsigned* maskS = (unsigned*)p; p += 2048 * 4;
    unsigned* maskE = (unsigned*)p; p += 1024 * 4;
    int* sumsS    = (int*)p;   p += 64 * 4;
    int* sumsE    = (int*)p;   p += 64 * 4;
    // prediction overlays on buffers dead after the layer-2 gathers:
    unsigned short* xhi = (unsigned short*)statAH;   // 8 MB needed <= 12.8 MB
    unsigned short* xlo = xhi + (size_t)B_N * K_N;
    unsigned short* w1hi = (unsigned short*)kdiffAH; // 256 KB needed <= 5.1 MB
    unsigned short* w1lo = w1hi + 32768;
    unsigned short* w2hi = w1lo + 32768;
    unsigned short* w2lo = w2hi + 32768;

    // ---- zero-init counters and masks ----
    hipMemsetAsync(cntS, 0, (size_t)S_N * 4, stream);
    hipMemsetAsync(cntE, 0, (size_t)E_N * 4, stream);
    hipMemsetAsync(maskS, 0, 2048 * 4, stream);
    hipMemsetAsync(maskE, 0, 1024 * 4, stream);

    // ---- fp16 embedding tables ----
    cvt_f16<<<((S_N + E_N) * 64 + 255) / 256, 256, 0, stream>>>(
        (const float2*)student_emb, (const float2*)exercise_emb, sEH, eEH);

    // ---- CSR build ----
    const int edgeChunks = (2 * NE_N + 255) / 256;  // 7813
    histogram_kernel<<<edgeChunks, 256, 0, stream>>>(rows_1, cols_1, rows_0, cols_0, cntS, cntE);
    const int nChunkS = (S_N + 1023) / 1024;        // 49
    const int nChunkE = (E_N + 1023) / 1024;        // 20
    scan_sums<<<nChunkS, 1024, 0, stream>>>(cntS, S_N, sumsS);
    scan_sums<<<nChunkE, 1024, 0, stream>>>(cntE, E_N, sumsE);
    scan_tops<<<1, 128, 0, stream>>>(sumsS, nChunkS, offS + S_N, sumsE, nChunkE, offE + E_N);
    scan_apply<<<nChunkS, 1024, 0, stream>>>(cntS, S_N, sumsS, offS, curS);
    scan_apply<<<nChunkE, 1024, 0, stream>>>(cntE, E_N, sumsE, offE, curE);
    fill_kernel_xcd<<<edgeChunks * 8, 256, 0, stream>>>(
        rows_1, cols_1, vals_ui_1, vals_iu_1,
        rows_0, cols_0, vals_ui_0, vals_iu_0,
        curS, curE, csrS, csrE);

    // ---- needed-row masks (for layer 2) ----
    mark_needed<<<(B_N + 255) / 256, 256, 0, stream>>>(stu_id, B_N, maskS);
    mark_needed<<<(B_N + 255) / 256, 256, 0, stream>>>(input_ex, B_N, maskE);

    const int sGrid = (S_N + 3) / 4;
    const int eGrid = (E_N + 3) / 4;

    // ---- layer 1: fp16 inputs -> A (all rows) ----
    gather_pass_h<<<sGrid, 256, 0, stream>>>(eEH, sEH, d_i_1, d_i_0,
                                             offS, csrS, nullptr, statAH, S_N);
    gather_pass_h<<<eGrid, 256, 0, stream>>>(sEH, eEH, d_j_1, d_j_0,
                                             offE, csrE, nullptr, kdiffAH, E_N);

    // ---- layer 2: A -> B (only rows the batch reads) ----
    gather_pass_h<<<sGrid, 256, 0, stream>>>(kdiffAH, statAH, d_i_1, d_i_0,
                                             offS, csrS, maskS, statBH, S_N);
    gather_pass_h<<<eGrid, 256, 0, stream>>>(statAH, kdiffAH, d_j_1, d_j_0,
                                             offE, csrE, maskE, kdiffBH, E_N);

    // ---- prediction: feature/weights -> split bf16, MFMA MLP ----
    // (overlays statAH/kdiffAH, so must run after the gathers)
    feature_kernel<<<B_N * 32 / 256, 256, 0, stream>>>(
        stu_id, input_ex, ikp, statBH, kdiffBH, s_bias, e_disc, xhi, xlo);
    abs_split_kernel<<<256, 256, 0, stream>>>(W1, W2, w1hi, w1lo, w2hi, w2lo);
    mlp_mfma<<<B_N / 32, 256, 0, stream>>>(xhi, xlo, w1hi, w1lo, w2hi, w2lo,
                                           b1, b2, W3, b3, (float*)d_out);
}